// Round 4
// baseline (3455.133 us; speedup 1.0000x reference)
//
#include <hip/hip_runtime.h>
#include <math.h>

#define B_SZ 2048
#define DIN  1024
#define H    2048
#define DOUT 1024
#define NEXP 8
#define NL   4

typedef _Float16 f16;
typedef _Float16 f16x4 __attribute__((ext_vector_type(4)));
typedef _Float16 f16x8 __attribute__((ext_vector_type(8)));
typedef __fp16   h16x2 __attribute__((ext_vector_type(2)));
typedef float    f32x4 __attribute__((ext_vector_type(4)));

#define MFMA16(a,b,c) __builtin_amdgcn_mfma_f32_16x16x32_f16((a),(b),(c),0,0,0)

// ---------------------------------------------------------------- convert x -> hi/lo
__global__ __launch_bounds__(256) void k_convert(const float* __restrict__ x,
                                                 f16* __restrict__ hi, f16* __restrict__ lo, int n4){
  int stride = gridDim.x * blockDim.x;
  for (int i = blockIdx.x*blockDim.x + threadIdx.x; i < n4; i += stride){
    float4 v = ((const float4*)x)[i];
    f16 h0=(f16)v.x, h1=(f16)v.y, h2=(f16)v.z, h3=(f16)v.w;
    f16x4 hv = {h0,h1,h2,h3};
    f16x4 lv = {(f16)((v.x-(float)h0)*2048.0f),(f16)((v.y-(float)h1)*2048.0f),
                (f16)((v.z-(float)h2)*2048.0f),(f16)((v.w-(float)h3)*2048.0f)};
    ((f16x4*)hi)[i] = hv;
    ((f16x4*)lo)[i] = lv;
  }
}

// ---------------------------------------------------------------- GEMM (split-fp16 precise or plain fp16)
// v3: A-fragments loaded DIRECTLY from global (L2/L3-resident), double-buffered in regs —
// LDS now holds only the B tile (fp32 W converted on write, x16 scaled). This halves LDS
// traffic, which round-3 analysis showed was the saturated pipe (~2300cy vs 1860cy MFMA).
template<int PRECISE>
__global__ __launch_bounds__(256, 2) void k_gemm(
    const f16* __restrict__ Ahi, const f16* __restrict__ Alo, int lda,
    const float* __restrict__ Wbase, const float* __restrict__ biasBase,
    int K, int N, int M,
    float* __restrict__ Cout, int ldc,
    const int* __restrict__ row_idx, const int* __restrict__ offsets,
    const int* __restrict__ tile_map, const int* __restrict__ ntiles,
    int wStride, int bStride)
{
  const bool ident = (tile_map == nullptr);
  int e, mt, roff, cnt;
  if (!ident){
    int ti = blockIdx.y;
    if (ti >= *ntiles) return;            // uniform early-exit before any barrier
    int mv = tile_map[ti]; e = mv >> 16; mt = mv & 0xffff;
    roff = offsets[e]; cnt = offsets[e+1] - roff;
  } else { e = 0; mt = blockIdx.y; roff = 0; cnt = M; }

  const float* W    = Wbase   + (size_t)e * wStride;
  const float* bias = biasBase+ (size_t)e * bStride;
  const int n0   = blockIdx.x * 128;
  const int tid  = threadIdx.x;
  const int lane = tid & 63;
  const int wid  = tid >> 6;
  const int wm   = (wid >> 1) * 64;
  const int wn   = (wid & 1) * 64;
  const int lr   = lane & 15;        // fragment row/col selector
  const int ks   = lane >> 4;        // k-slot (0..3) of 8 f16

  __shared__ f16x8 sBh[128*5];
  __shared__ f16x8 sBl[PRECISE ? 128*5 : 1];

  // ---- A fragment bases: lane holds A[row(lr)][k + ks*8 ..+8], row = wave row + mf*16
  const f16* aBh[4]; const f16* aBl[4];
  #pragma unroll
  for (int mf = 0; mf < 4; mf++){
    int ridx = mt*128 + wm + mf*16 + lr;
    int gr;
    if (ident) gr = ridx;
    else       gr = row_idx[roff + (ridx < cnt ? ridx : 0)];
    aBh[mf] = Ahi + (size_t)gr*lda + ks*8;
    if constexpr (PRECISE) aBl[mf] = Alo + (size_t)gr*lda + ks*8;
  }

  // ---- B staging: thread owns col bn (0..127) and k-half kb (0/1): 16 k's
  const int bn = tid & 127, kb = tid >> 7;
  const float* wp0 = W + (size_t)(kb*16) * N + n0 + bn;

  f32x4 acc0[4][4] = {};
  f32x4 acc1[4][4] = {};

  float rW[16];
  auto issueB = [&](int kk){
    const float* wp = wp0 + (size_t)kk * N;
    #pragma unroll
    for (int i = 0; i < 16; i++) rW[i] = wp[(size_t)i * N];
  };

  f16x8 aH0[4], aL0[4], aH1[4], aL1[4];
  auto loadA = [&](f16x8* aH, f16x8* aL, int kk){
    #pragma unroll
    for (int mf = 0; mf < 4; mf++){
      aH[mf] = *(const f16x8*)(aBh[mf] + kk);
      if constexpr (PRECISE) aL[mf] = *(const f16x8*)(aBl[mf] + kk);
    }
  };

  auto step = [&](int kk, f16x8* aHc, f16x8* aLc, f16x8* aHn, f16x8* aLn){
    // ---- write-B phase: consume rW for step kk
    {
      f16 hs[16], ls[16];
      #pragma unroll
      for (int i = 0; i < 16; i += 2){
        float w0 = rW[i]   * 16.0f;      // x16: keep fp16-lo comfortably normal
        float w1 = rW[i+1] * 16.0f;
        h16x2 hp = __builtin_amdgcn_cvt_pkrtz(w0, w1);
        hs[i] = (f16)hp.x; hs[i+1] = (f16)hp.y;
        if constexpr (PRECISE){
          h16x2 lp = __builtin_amdgcn_cvt_pkrtz((w0-(float)hp.x)*2048.0f,
                                                (w1-(float)hp.y)*2048.0f);
          ls[i] = (f16)lp.x; ls[i+1] = (f16)lp.y;
        }
      }
      f16x8 v0 = {hs[0],hs[1],hs[2],hs[3],hs[4],hs[5],hs[6],hs[7]};
      f16x8 v1 = {hs[8],hs[9],hs[10],hs[11],hs[12],hs[13],hs[14],hs[15]};
      sBh[bn*5 + kb*2 + 0] = v0;
      sBh[bn*5 + kb*2 + 1] = v1;
      if constexpr (PRECISE){
        f16x8 u0 = {ls[0],ls[1],ls[2],ls[3],ls[4],ls[5],ls[6],ls[7]};
        f16x8 u1 = {ls[8],ls[9],ls[10],ls[11],ls[12],ls[13],ls[14],ls[15]};
        sBl[bn*5 + kb*2 + 0] = u0;
        sBl[bn*5 + kb*2 + 1] = u1;
      }
    }
    __syncthreads();

    // ---- prefetch next step: W into rW, A-frags into the alternate reg buffer
    if (kk + 32 < K){
      issueB(kk + 32);
      loadA(aHn, aLn, kk + 32);
    }

    // ---- compute phase
    #pragma unroll
    for (int nf = 0; nf < 4; nf++){
      int col = wn + nf*16 + lr;
      f16x8 bh = sBh[col*5 + ks];
      f16x8 bl;
      if constexpr (PRECISE) bl = sBl[col*5 + ks];
      #pragma unroll
      for (int mf = 0; mf < 4; mf++){
        acc0[mf][nf] = MFMA16(aHc[mf], bh, acc0[mf][nf]);
        if constexpr (PRECISE){
          acc1[mf][nf] = MFMA16(aHc[mf], bl, acc1[mf][nf]);
          acc1[mf][nf] = MFMA16(aLc[mf], bh, acc1[mf][nf]);
        }
      }
    }
    __syncthreads();
  };

  issueB(0);
  loadA(aH0, aL0, 0);
  for (int k0 = 0; k0 < K; k0 += 64){
    step(k0,      aH0, aL0, aH1, aL1);
    step(k0 + 32, aH1, aL1, aH0, aL0);
  }

  // epilogue: val = (acc0 + acc1/2048)/16 + bias, relu, scatter-store
  const float s1 = 1.0f/16.0f, s2 = 1.0f/(16.0f*2048.0f);
  float bvs[4];
  #pragma unroll
  for (int nf = 0; nf < 4; nf++) bvs[nf] = bias[n0 + wn + nf*16 + lr];
  #pragma unroll
  for (int mf = 0; mf < 4; mf++){
    #pragma unroll
    for (int j = 0; j < 4; j++){
      int rt   = wm + mf*16 + (lane >> 4)*4 + j;
      int ridx = mt*128 + rt;
      int gr; bool valid;
      if (ident){ gr = ridx; valid = true; }
      else { valid = (ridx < cnt); gr = valid ? row_idx[roff + ridx] : 0; }
      if (valid){
        float* cp = Cout + (size_t)gr*ldc + n0 + wn + lr;
        #pragma unroll
        for (int nf = 0; nf < 4; nf++){
          float v = acc0[mf][nf][j]*s1 + bvs[nf];
          if constexpr (PRECISE) v += acc1[mf][nf][j]*s2;
          v = v > 0.0f ? v : 0.0f;
          cp[nf*16] = v;
        }
      }
    }
  }
}

// ---------------------------------------------------------------- BN stats (partial sums per row-chunk)
__global__ __launch_bounds__(256) void k_stats(const float* __restrict__ P,
                                               float* __restrict__ psum, float* __restrict__ psq){
  int c  = blockIdx.x*64 + (threadIdx.x & 63);
  int rs = threadIdx.x >> 6;
  int r0 = blockIdx.y * 256;
  float s = 0.f, q = 0.f;
  for (int r = r0 + rs; r < r0 + 256; r += 4){
    float v = P[(size_t)r*H + c]; s += v; q += v*v;
  }
  __shared__ float ls[4][64], lq[4][64];
  ls[rs][threadIdx.x & 63] = s; lq[rs][threadIdx.x & 63] = q;
  __syncthreads();
  if (threadIdx.x < 64){
    int cc = threadIdx.x;
    float S = ls[0][cc]+ls[1][cc]+ls[2][cc]+ls[3][cc];
    float Q = lq[0][cc]+lq[1][cc]+lq[2][cc]+lq[3][cc];
    psum[(size_t)blockIdx.y*H + blockIdx.x*64 + cc] = S;
    psq [(size_t)blockIdx.y*H + blockIdx.x*64 + cc] = Q;
  }
}

// ---------------------------------------------------------------- BN normalize -> write fp16 hi/lo
__global__ __launch_bounds__(256) void k_norm(const float* __restrict__ P,
    const float* __restrict__ psum, const float* __restrict__ psq,
    const float* __restrict__ gamma, const float* __restrict__ beta,
    f16* __restrict__ Hhi, f16* __restrict__ Hlo){
  __shared__ float sS[64], sT[64];
  int c0 = blockIdx.x * 64;
  int tid = threadIdx.x;
  if (tid < 64){
    float s = 0.f, q = 0.f;
    #pragma unroll
    for (int j = 0; j < 8; j++){ s += psum[(size_t)j*H + c0 + tid]; q += psq[(size_t)j*H + c0 + tid]; }
    float mu  = s * (1.0f/B_SZ);
    float var = q * (1.0f/B_SZ) - mu*mu; var = var > 0.f ? var : 0.f;
    float r   = 1.0f / sqrtf(var + 1e-5f);
    float g   = gamma[c0 + tid] * r;
    sS[tid] = g; sT[tid] = beta[c0 + tid] - mu*g;
  }
  __syncthreads();
  int cg = (tid & 15) * 4;
  int r0 = blockIdx.y * 256;
  for (int r = r0 + (tid >> 4); r < r0 + 256; r += 16){
    float4 v = *(const float4*)&P[(size_t)r*H + c0 + cg];
    float h0 = v.x*sS[cg]   + sT[cg];
    float h1 = v.y*sS[cg+1] + sT[cg+1];
    float h2 = v.z*sS[cg+2] + sT[cg+2];
    float h3 = v.w*sS[cg+3] + sT[cg+3];
    f16 a0=(f16)h0, a1=(f16)h1, a2=(f16)h2, a3=(f16)h3;
    f16x4 hv = {a0,a1,a2,a3};
    f16x4 lv = {(f16)((h0-(float)a0)*2048.0f),(f16)((h1-(float)a1)*2048.0f),
                (f16)((h2-(float)a2)*2048.0f),(f16)((h3-(float)a3)*2048.0f)};
    *(f16x4*)&Hhi[(size_t)r*H + c0 + cg] = hv;
    *(f16x4*)&Hlo[(size_t)r*H + c0 + cg] = lv;
  }
}

// ---------------------------------------------------------------- logits + argmax (exact fp32, vectorized)
__global__ __launch_bounds__(256) void k_logits(const f16* __restrict__ Hhi, const f16* __restrict__ Hlo,
    const float* __restrict__ dqnW, const float* __restrict__ dqnB, int* __restrict__ actions){
  int row  = blockIdx.x*4 + (threadIdx.x >> 6);
  int lane = threadIdx.x & 63;
  float acc[8] = {0,0,0,0,0,0,0,0};
  const f16* ph = Hhi + (size_t)row*H;
  const f16* pl = Hlo + (size_t)row*H;
  #pragma unroll
  for (int t = 0; t < 4; t++){
    int k = t*512 + lane*8;
    f16x8 h8 = *(const f16x8*)(ph + k);
    f16x8 l8 = *(const f16x8*)(pl + k);
    #pragma unroll
    for (int j = 0; j < 8; j++){
      float h = (float)h8[j] + (float)l8[j]*(1.0f/2048.0f);
      const float* w = dqnW + (size_t)(k+j)*NEXP;
      float4 w0 = *(const float4*)w;
      float4 w1 = *(const float4*)(w+4);
      acc[0] += h*w0.x; acc[1] += h*w0.y; acc[2] += h*w0.z; acc[3] += h*w0.w;
      acc[4] += h*w1.x; acc[5] += h*w1.y; acc[6] += h*w1.z; acc[7] += h*w1.w;
    }
  }
  #pragma unroll
  for (int off = 32; off; off >>= 1){
    #pragma unroll
    for (int e2 = 0; e2 < 8; e2++) acc[e2] += __shfl_down(acc[e2], off);
  }
  if (lane == 0){
    float best = acc[0] + dqnB[0]; int bi = 0;
    #pragma unroll
    for (int e2 = 1; e2 < 8; e2++){ float v = acc[e2] + dqnB[e2]; if (v > best){ best = v; bi = e2; } }
    actions[row] = bi;
  }
}

// ---------------------------------------------------------------- routing: count/scan/scatter/tile-map
__global__ __launch_bounds__(256) void k_route(const int* __restrict__ actions, int* __restrict__ offsets,
    int* __restrict__ row_idx, int* __restrict__ tile_map, int* __restrict__ ntiles){
  __shared__ int cnt[8], cur[8];
  int tid = threadIdx.x;
  if (tid < 8) cnt[tid] = 0;
  __syncthreads();
  for (int b = tid; b < B_SZ; b += 256) atomicAdd(&cnt[actions[b]], 1);
  __syncthreads();
  if (tid == 0){
    int o = 0, nt = 0;
    for (int e2 = 0; e2 < 8; e2++){
      offsets[e2] = o; cur[e2] = o;
      int c = cnt[e2];
      int t = (c + 127) >> 7;
      for (int ti = 0; ti < t; ti++) tile_map[nt++] = (e2 << 16) | ti;
      o += c;
    }
    offsets[8] = o;
    *ntiles = nt;
  }
  __syncthreads();
  for (int b = tid; b < B_SZ; b += 256){
    int a = actions[b];
    int p = atomicAdd(&cur[a], 1);
    row_idx[p] = b;
  }
}

// ---------------------------------------------------------------- launch
extern "C" void kernel_launch(void* const* d_in, const int* in_sizes, int n_in,
                              void* d_out, int out_size, void* d_ws, size_t ws_size,
                              hipStream_t stream){
  const float* x           = (const float*)d_in[0];
  const float* start_W     = (const float*)d_in[1];
  const float* start_b     = (const float*)d_in[2];
  const float* start_gamma = (const float*)d_in[3];
  const float* start_beta  = (const float*)d_in[4];
  const float* expert_W    = (const float*)d_in[5];
  const float* expert_b    = (const float*)d_in[6];
  const float* bn_gamma    = (const float*)d_in[7];
  const float* bn_beta     = (const float*)d_in[8];
  const float* dqn_W       = (const float*)d_in[9];
  const float* dqn_b       = (const float*)d_in[10];
  const float* end_W       = (const float*)d_in[11];
  const float* end_b       = (const float*)d_in[12];
  float* out = (float*)d_out;

  char* ws = (char*)d_ws;
  size_t off = 0;
  auto alloc = [&](size_t bytes){ void* p = ws + off; off += (bytes + 255) & ~(size_t)255; return p; };
  f16*   Hhi     = (f16*)  alloc((size_t)B_SZ*H*2);
  f16*   Hlo     = (f16*)  alloc((size_t)B_SZ*H*2);
  float* Ppre    = (float*)alloc((size_t)B_SZ*H*4);
  float* psum    = (float*)alloc((size_t)8*H*4);
  float* psq     = (float*)alloc((size_t)8*H*4);
  int*   actions = (int*)  alloc(B_SZ*4);
  int*   row_idx = (int*)  alloc(B_SZ*4);
  int*   offsets = (int*)  alloc(16*4);
  int*   tile_map= (int*)  alloc(32*4);
  int*   ntiles  = (int*)  alloc(64);

  // start: x -> hi/lo, precise GEMM, BN
  k_convert<<<512, 256, 0, stream>>>(x, Hhi, Hlo, B_SZ*DIN/4);
  k_gemm<1><<<dim3(H/128, B_SZ/128), 256, 0, stream>>>(
      Hhi, Hlo, DIN, start_W, start_b, DIN, H, B_SZ, Ppre, H,
      nullptr, nullptr, nullptr, nullptr, 0, 0);
  k_stats<<<dim3(H/64, 8), 256, 0, stream>>>(Ppre, psum, psq);
  k_norm <<<dim3(H/64, 8), 256, 0, stream>>>(Ppre, psum, psq, start_gamma, start_beta, Hhi, Hlo);

  for (int i = 0; i < NL; i++){
    k_logits<<<B_SZ/4, 256, 0, stream>>>(Hhi, Hlo, dqn_W, dqn_b, actions);
    k_route <<<1, 256, 0, stream>>>(actions, offsets, row_idx, tile_map, ntiles);
    const float* Wb = expert_W + (size_t)i*NEXP*H*H;
    const float* bb = expert_b + (size_t)i*NEXP*H;
    if (i < 3)
      k_gemm<1><<<dim3(H/128, 23), 256, 0, stream>>>(
          Hhi, Hlo, H, Wb, bb, H, H, B_SZ, Ppre, H,
          row_idx, offsets, tile_map, ntiles, H*H, H);
    else
      k_gemm<0><<<dim3(H/128, 23), 256, 0, stream>>>(
          Hhi, nullptr, H, Wb, bb, H, H, B_SZ, Ppre, H,
          row_idx, offsets, tile_map, ntiles, H*H, H);
    k_stats<<<dim3(H/64, 8), 256, 0, stream>>>(Ppre, psum, psq);
    k_norm <<<dim3(H/64, 8), 256, 0, stream>>>(Ppre, psum, psq,
        bn_gamma + (size_t)i*H, bn_beta + (size_t)i*H, Hhi, Hlo);
  }

  // end: plain fp16 GEMM -> d_out
  k_gemm<0><<<dim3(DOUT/128, B_SZ/128), 256, 0, stream>>>(
      Hhi, nullptr, H, end_W, end_b, H, DOUT, B_SZ, out, DOUT,
      nullptr, nullptr, nullptr, nullptr, 0, 0);
}

// Round 5
// 742.497 us; speedup vs baseline: 4.6534x; 4.6534x over previous
//
#include <hip/hip_runtime.h>
#include <math.h>

#define B_SZ 2048
#define DIN  1024
#define H    2048
#define DOUT 1024
#define NEXP 8
#define NL   4

typedef _Float16 f16;
typedef _Float16 f16x4 __attribute__((ext_vector_type(4)));
typedef _Float16 f16x8 __attribute__((ext_vector_type(8)));
typedef __fp16   h16x2 __attribute__((ext_vector_type(2)));
typedef float    f32x4 __attribute__((ext_vector_type(4)));

#define MFMA16(a,b,c) __builtin_amdgcn_mfma_f32_16x16x32_f16((a),(b),(c),0,0,0)

// ---------------------------------------------------------------- convert x -> hi/lo
__global__ __launch_bounds__(256) void k_convert(const float* __restrict__ x,
                                                 f16* __restrict__ hi, f16* __restrict__ lo, int n4){
  int stride = gridDim.x * blockDim.x;
  for (int i = blockIdx.x*blockDim.x + threadIdx.x; i < n4; i += stride){
    float4 v = ((const float4*)x)[i];
    f16 h0=(f16)v.x, h1=(f16)v.y, h2=(f16)v.z, h3=(f16)v.w;
    f16x4 hv = {h0,h1,h2,h3};
    f16x4 lv = {(f16)((v.x-(float)h0)*2048.0f),(f16)((v.y-(float)h1)*2048.0f),
                (f16)((v.z-(float)h2)*2048.0f),(f16)((v.w-(float)h3)*2048.0f)};
    ((f16x4*)hi)[i] = hv;
    ((f16x4*)lo)[i] = lv;
  }
}

// ---------------------------------------------------------------- GEMM (split-fp16 precise or plain fp16)
// v5 = round-3 structure (A+B through LDS, reg-prefetched one K-step ahead — 755us known-good)
// + 1-D grid with bijective XCD-cluster swizzle: consecutive logical blocks = the 16 n-slices
// of ONE m-tile, clustered on ONE XCD so the A hi/lo panel (1MB) is fetched into that XCD's
// L2 once instead of once per XCD (A traffic 134MB -> ~17MB per layer).
template<int PRECISE>
__global__ __launch_bounds__(256, 2) void k_gemm(
    const f16* __restrict__ Ahi, const f16* __restrict__ Alo, int lda,
    const float* __restrict__ Wbase, const float* __restrict__ biasBase,
    int K, int N, int M, int nTx,
    float* __restrict__ Cout, int ldc,
    const int* __restrict__ row_idx, const int* __restrict__ offsets,
    const int* __restrict__ tile_map, const int* __restrict__ ntiles,
    int wStride, int bStride)
{
  // ---- XCD-cluster swizzle (grid is always a multiple of 8)
  const int q = gridDim.x >> 3;
  const int logical = (blockIdx.x & 7) * q + (blockIdx.x >> 3);
  const int ntile_x = logical % nTx;          // n-slice index
  const int mtile_l = logical / nTx;          // m-tile (or tile_map index)

  const bool ident = (tile_map == nullptr);
  int e, mt, roff, cnt;
  if (!ident){
    if (mtile_l >= *ntiles) return;           // uniform early-exit before any barrier
    int mv = tile_map[mtile_l]; e = mv >> 16; mt = mv & 0xffff;
    roff = offsets[e]; cnt = offsets[e+1] - roff;
  } else { e = 0; mt = mtile_l; roff = 0; cnt = M; }

  const float* W    = Wbase   + (size_t)e * wStride;
  const float* bias = biasBase+ (size_t)e * bStride;
  const int n0   = ntile_x * 128;
  const int tid  = threadIdx.x;
  const int lane = tid & 63;
  const int wid  = tid >> 6;
  const int wm   = (wid >> 1) * 64;
  const int wn   = (wid & 1) * 64;

  __shared__ f16x8 sAh[128*5];
  __shared__ f16x8 sAl[PRECISE ? 128*5 : 1];
  __shared__ f16x8 sBh[128*5];
  __shared__ f16x8 sBl[PRECISE ? 128*5 : 1];

  // A staging: 512 tasks (128 rows x 4 slots of 16B), 2 per thread
  const int r1 = tid >> 2, sl = tid & 3, r2 = r1 + 64;
  int gr1, gr2;
  {
    int i1 = mt*128 + r1, i2 = mt*128 + r2;
    if (ident){ gr1 = i1; gr2 = i2; }
    else { gr1 = row_idx[roff + (i1 < cnt ? i1 : 0)];
           gr2 = row_idx[roff + (i2 < cnt ? i2 : 0)]; }
  }
  const f16* a1h = Ahi + (size_t)gr1*lda + sl*8;
  const f16* a2h = Ahi + (size_t)gr2*lda + sl*8;
  const f16 *a1l = nullptr, *a2l = nullptr;
  if constexpr (PRECISE){
    a1l = Alo + (size_t)gr1*lda + sl*8;
    a2l = Alo + (size_t)gr2*lda + sl*8;
  }

  // B staging: thread owns col n (0..127) and k-half kb (0/1): 16 k's
  const int bn = tid & 127, kb = tid >> 7;
  const float* wp0 = W + (size_t)(kb*16) * N + n0 + bn;

  f32x4 acc0[4][4] = {};
  f32x4 acc1[4][4] = {};

  // register prefetch state
  f16x8 rA1h, rA2h, rA1l, rA2l;
  float rW[16];

  auto issue = [&](int kk){
    rA1h = *(const f16x8*)(a1h + kk);
    rA2h = *(const f16x8*)(a2h + kk);
    if constexpr (PRECISE){
      rA1l = *(const f16x8*)(a1l + kk);
      rA2l = *(const f16x8*)(a2l + kk);
    }
    const float* wp = wp0 + (size_t)kk * N;
    #pragma unroll
    for (int i = 0; i < 16; i++) rW[i] = wp[(size_t)i * N];
  };

  issue(0);

  for (int k0 = 0; k0 < K; k0 += 32){
    // ---- write phase: consume regs for step k0
    sAh[r1*5 + sl] = rA1h;
    sAh[r2*5 + sl] = rA2h;
    if constexpr (PRECISE){
      sAl[r1*5 + sl] = rA1l;
      sAl[r2*5 + sl] = rA2l;
    }
    {
      f16 hs[16], ls[16];
      #pragma unroll
      for (int i = 0; i < 16; i += 2){
        float w0 = rW[i]   * 16.0f;      // x16: keep fp16-lo comfortably normal
        float w1 = rW[i+1] * 16.0f;
        h16x2 hp = __builtin_amdgcn_cvt_pkrtz(w0, w1);
        hs[i] = (f16)hp.x; hs[i+1] = (f16)hp.y;
        if constexpr (PRECISE){
          h16x2 lp = __builtin_amdgcn_cvt_pkrtz((w0-(float)hp.x)*2048.0f,
                                                (w1-(float)hp.y)*2048.0f);
          ls[i] = (f16)lp.x; ls[i+1] = (f16)lp.y;
        }
      }
      f16x8 v0 = {hs[0],hs[1],hs[2],hs[3],hs[4],hs[5],hs[6],hs[7]};
      f16x8 v1 = {hs[8],hs[9],hs[10],hs[11],hs[12],hs[13],hs[14],hs[15]};
      sBh[bn*5 + kb*2 + 0] = v0;
      sBh[bn*5 + kb*2 + 1] = v1;
      if constexpr (PRECISE){
        f16x8 u0 = {ls[0],ls[1],ls[2],ls[3],ls[4],ls[5],ls[6],ls[7]};
        f16x8 u1 = {ls[8],ls[9],ls[10],ls[11],ls[12],ls[13],ls[14],ls[15]};
        sBl[bn*5 + kb*2 + 0] = u0;
        sBl[bn*5 + kb*2 + 1] = u1;
      }
    }
    __syncthreads();

    // ---- issue next step's loads early: latency hides under the MFMA phase
    if (k0 + 32 < K) issue(k0 + 32);

    // ---- compute phase
    f16x8 ah[4], al[4];
    #pragma unroll
    for (int mf = 0; mf < 4; mf++){
      int row = wm + mf*16 + (lane & 15);
      ah[mf] = sAh[row*5 + (lane >> 4)];
      if constexpr (PRECISE) al[mf] = sAl[row*5 + (lane >> 4)];
    }
    #pragma unroll
    for (int nf = 0; nf < 4; nf++){
      int col = wn + nf*16 + (lane & 15);
      f16x8 bh = sBh[col*5 + (lane >> 4)];
      f16x8 bl;
      if constexpr (PRECISE) bl = sBl[col*5 + (lane >> 4)];
      #pragma unroll
      for (int mf = 0; mf < 4; mf++){
        acc0[mf][nf] = MFMA16(ah[mf], bh, acc0[mf][nf]);
        if constexpr (PRECISE){
          acc1[mf][nf] = MFMA16(ah[mf], bl, acc1[mf][nf]);
          acc1[mf][nf] = MFMA16(al[mf], bh, acc1[mf][nf]);
        }
      }
    }
    __syncthreads();
  }

  // epilogue: val = (acc0 + acc1/2048)/16 + bias, relu, scatter-store
  const float s1 = 1.0f/16.0f, s2 = 1.0f/(16.0f*2048.0f);
  float bvs[4];
  #pragma unroll
  for (int nf = 0; nf < 4; nf++) bvs[nf] = bias[n0 + wn + nf*16 + (lane & 15)];
  #pragma unroll
  for (int mf = 0; mf < 4; mf++){
    #pragma unroll
    for (int j = 0; j < 4; j++){
      int rt   = wm + mf*16 + (lane >> 4)*4 + j;
      int ridx = mt*128 + rt;
      int gr; bool valid;
      if (ident){ gr = ridx; valid = true; }
      else { valid = (ridx < cnt); gr = valid ? row_idx[roff + ridx] : 0; }
      if (valid){
        float* cp = Cout + (size_t)gr*ldc + n0 + wn + (lane & 15);
        #pragma unroll
        for (int nf = 0; nf < 4; nf++){
          float v = acc0[mf][nf][j]*s1 + bvs[nf];
          if constexpr (PRECISE) v += acc1[mf][nf][j]*s2;
          v = v > 0.0f ? v : 0.0f;
          cp[nf*16] = v;
        }
      }
    }
  }
}

// ---------------------------------------------------------------- BN stats (partial sums per row-chunk)
__global__ __launch_bounds__(256) void k_stats(const float* __restrict__ P,
                                               float* __restrict__ psum, float* __restrict__ psq){
  int c  = blockIdx.x*64 + (threadIdx.x & 63);
  int rs = threadIdx.x >> 6;
  int r0 = blockIdx.y * 256;
  float s = 0.f, q = 0.f;
  for (int r = r0 + rs; r < r0 + 256; r += 4){
    float v = P[(size_t)r*H + c]; s += v; q += v*v;
  }
  __shared__ float ls[4][64], lq[4][64];
  ls[rs][threadIdx.x & 63] = s; lq[rs][threadIdx.x & 63] = q;
  __syncthreads();
  if (threadIdx.x < 64){
    int cc = threadIdx.x;
    float S = ls[0][cc]+ls[1][cc]+ls[2][cc]+ls[3][cc];
    float Q = lq[0][cc]+lq[1][cc]+lq[2][cc]+lq[3][cc];
    psum[(size_t)blockIdx.y*H + blockIdx.x*64 + cc] = S;
    psq [(size_t)blockIdx.y*H + blockIdx.x*64 + cc] = Q;
  }
}

// ---------------------------------------------------------------- BN normalize -> write fp16 hi/lo
__global__ __launch_bounds__(256) void k_norm(const float* __restrict__ P,
    const float* __restrict__ psum, const float* __restrict__ psq,
    const float* __restrict__ gamma, const float* __restrict__ beta,
    f16* __restrict__ Hhi, f16* __restrict__ Hlo){
  __shared__ float sS[64], sT[64];
  int c0 = blockIdx.x * 64;
  int tid = threadIdx.x;
  if (tid < 64){
    float s = 0.f, q = 0.f;
    #pragma unroll
    for (int j = 0; j < 8; j++){ s += psum[(size_t)j*H + c0 + tid]; q += psq[(size_t)j*H + c0 + tid]; }
    float mu  = s * (1.0f/B_SZ);
    float var = q * (1.0f/B_SZ) - mu*mu; var = var > 0.f ? var : 0.f;
    float r   = 1.0f / sqrtf(var + 1e-5f);
    float g   = gamma[c0 + tid] * r;
    sS[tid] = g; sT[tid] = beta[c0 + tid] - mu*g;
  }
  __syncthreads();
  int cg = (tid & 15) * 4;
  int r0 = blockIdx.y * 256;
  for (int r = r0 + (tid >> 4); r < r0 + 256; r += 16){
    float4 v = *(const float4*)&P[(size_t)r*H + c0 + cg];
    float h0 = v.x*sS[cg]   + sT[cg];
    float h1 = v.y*sS[cg+1] + sT[cg+1];
    float h2 = v.z*sS[cg+2] + sT[cg+2];
    float h3 = v.w*sS[cg+3] + sT[cg+3];
    f16 a0=(f16)h0, a1=(f16)h1, a2=(f16)h2, a3=(f16)h3;
    f16x4 hv = {a0,a1,a2,a3};
    f16x4 lv = {(f16)((h0-(float)a0)*2048.0f),(f16)((h1-(float)a1)*2048.0f),
                (f16)((h2-(float)a2)*2048.0f),(f16)((h3-(float)a3)*2048.0f)};
    *(f16x4*)&Hhi[(size_t)r*H + c0 + cg] = hv;
    *(f16x4*)&Hlo[(size_t)r*H + c0 + cg] = lv;
  }
}

// ---------------------------------------------------------------- logits + argmax (exact fp32, vectorized)
__global__ __launch_bounds__(256) void k_logits(const f16* __restrict__ Hhi, const f16* __restrict__ Hlo,
    const float* __restrict__ dqnW, const float* __restrict__ dqnB, int* __restrict__ actions){
  int row  = blockIdx.x*4 + (threadIdx.x >> 6);
  int lane = threadIdx.x & 63;
  float acc[8] = {0,0,0,0,0,0,0,0};
  const f16* ph = Hhi + (size_t)row*H;
  const f16* pl = Hlo + (size_t)row*H;
  #pragma unroll
  for (int t = 0; t < 4; t++){
    int k = t*512 + lane*8;
    f16x8 h8 = *(const f16x8*)(ph + k);
    f16x8 l8 = *(const f16x8*)(pl + k);
    #pragma unroll
    for (int j = 0; j < 8; j++){
      float h = (float)h8[j] + (float)l8[j]*(1.0f/2048.0f);
      const float* w = dqnW + (size_t)(k+j)*NEXP;
      float4 w0 = *(const float4*)w;
      float4 w1 = *(const float4*)(w+4);
      acc[0] += h*w0.x; acc[1] += h*w0.y; acc[2] += h*w0.z; acc[3] += h*w0.w;
      acc[4] += h*w1.x; acc[5] += h*w1.y; acc[6] += h*w1.z; acc[7] += h*w1.w;
    }
  }
  #pragma unroll
  for (int off = 32; off; off >>= 1){
    #pragma unroll
    for (int e2 = 0; e2 < 8; e2++) acc[e2] += __shfl_down(acc[e2], off);
  }
  if (lane == 0){
    float best = acc[0] + dqnB[0]; int bi = 0;
    #pragma unroll
    for (int e2 = 1; e2 < 8; e2++){ float v = acc[e2] + dqnB[e2]; if (v > best){ best = v; bi = e2; } }
    actions[row] = bi;
  }
}

// ---------------------------------------------------------------- routing: count/scan/scatter/tile-map
__global__ __launch_bounds__(256) void k_route(const int* __restrict__ actions, int* __restrict__ offsets,
    int* __restrict__ row_idx, int* __restrict__ tile_map, int* __restrict__ ntiles){
  __shared__ int cnt[8], cur[8];
  int tid = threadIdx.x;
  if (tid < 8) cnt[tid] = 0;
  __syncthreads();
  for (int b = tid; b < B_SZ; b += 256) atomicAdd(&cnt[actions[b]], 1);
  __syncthreads();
  if (tid == 0){
    int o = 0, nt = 0;
    for (int e2 = 0; e2 < 8; e2++){
      offsets[e2] = o; cur[e2] = o;
      int c = cnt[e2];
      int t = (c + 127) >> 7;
      for (int ti = 0; ti < t; ti++) tile_map[nt++] = (e2 << 16) | ti;
      o += c;
    }
    offsets[8] = o;
    *ntiles = nt;
  }
  __syncthreads();
  for (int b = tid; b < B_SZ; b += 256){
    int a = actions[b];
    int p = atomicAdd(&cur[a], 1);
    row_idx[p] = b;
  }
}

// ---------------------------------------------------------------- launch
extern "C" void kernel_launch(void* const* d_in, const int* in_sizes, int n_in,
                              void* d_out, int out_size, void* d_ws, size_t ws_size,
                              hipStream_t stream){
  const float* x           = (const float*)d_in[0];
  const float* start_W     = (const float*)d_in[1];
  const float* start_b     = (const float*)d_in[2];
  const float* start_gamma = (const float*)d_in[3];
  const float* start_beta  = (const float*)d_in[4];
  const float* expert_W    = (const float*)d_in[5];
  const float* expert_b    = (const float*)d_in[6];
  const float* bn_gamma    = (const float*)d_in[7];
  const float* bn_beta     = (const float*)d_in[8];
  const float* dqn_W       = (const float*)d_in[9];
  const float* dqn_b       = (const float*)d_in[10];
  const float* end_W       = (const float*)d_in[11];
  const float* end_b       = (const float*)d_in[12];
  float* out = (float*)d_out;

  char* ws = (char*)d_ws;
  size_t off = 0;
  auto alloc = [&](size_t bytes){ void* p = ws + off; off += (bytes + 255) & ~(size_t)255; return p; };
  f16*   Hhi     = (f16*)  alloc((size_t)B_SZ*H*2);
  f16*   Hlo     = (f16*)  alloc((size_t)B_SZ*H*2);
  float* Ppre    = (float*)alloc((size_t)B_SZ*H*4);
  float* psum    = (float*)alloc((size_t)8*H*4);
  float* psq     = (float*)alloc((size_t)8*H*4);
  int*   actions = (int*)  alloc(B_SZ*4);
  int*   row_idx = (int*)  alloc(B_SZ*4);
  int*   offsets = (int*)  alloc(16*4);
  int*   tile_map= (int*)  alloc(32*4);
  int*   ntiles  = (int*)  alloc(64);

  // start: x -> hi/lo, precise GEMM, BN   (grid = m-tiles x n-tiles, 1-D, multiple of 8)
  k_convert<<<512, 256, 0, stream>>>(x, Hhi, Hlo, B_SZ*DIN/4);
  k_gemm<1><<<(B_SZ/128)*(H/128), 256, 0, stream>>>(
      Hhi, Hlo, DIN, start_W, start_b, DIN, H, B_SZ, H/128, Ppre, H,
      nullptr, nullptr, nullptr, nullptr, 0, 0);
  k_stats<<<dim3(H/64, 8), 256, 0, stream>>>(Ppre, psum, psq);
  k_norm <<<dim3(H/64, 8), 256, 0, stream>>>(Ppre, psum, psq, start_gamma, start_beta, Hhi, Hlo);

  for (int i = 0; i < NL; i++){
    k_logits<<<B_SZ/4, 256, 0, stream>>>(Hhi, Hlo, dqn_W, dqn_b, actions);
    k_route <<<1, 256, 0, stream>>>(actions, offsets, row_idx, tile_map, ntiles);
    const float* Wb = expert_W + (size_t)i*NEXP*H*H;
    const float* bb = expert_b + (size_t)i*NEXP*H;
    if (i < 3)
      k_gemm<1><<<23*(H/128), 256, 0, stream>>>(
          Hhi, Hlo, H, Wb, bb, H, H, B_SZ, H/128, Ppre, H,
          row_idx, offsets, tile_map, ntiles, H*H, H);
    else
      k_gemm<0><<<23*(H/128), 256, 0, stream>>>(
          Hhi, nullptr, H, Wb, bb, H, H, B_SZ, H/128, Ppre, H,
          row_idx, offsets, tile_map, ntiles, H*H, H);
    k_stats<<<dim3(H/64, 8), 256, 0, stream>>>(Ppre, psum, psq);
    k_norm <<<dim3(H/64, 8), 256, 0, stream>>>(Ppre, psum, psq,
        bn_gamma + (size_t)i*H, bn_beta + (size_t)i*H, Hhi, Hlo);
  }

  // end: plain fp16 GEMM -> d_out
  k_gemm<0><<<(B_SZ/128)*(DOUT/128), 256, 0, stream>>>(
      Hhi, nullptr, H, end_W, end_b, H, DOUT, B_SZ, DOUT/128, out, DOUT,
      nullptr, nullptr, nullptr, nullptr, 0, 0);
}